// Round 13
// baseline (329.927 us; speedup 1.0000x reference)
//
#include <hip/hip_runtime.h>

#define B_ 8
#define N_ 100000
#define C_ 64
#define K_ 300000          // N*3 flattened reduction dim
#define K4_ (K_/4)         // 75000 float4 per (b,c) row
#define AP_BLK ((K4_ + 255)/256)  // 293

#define KB 128             // pass1 K-tile (bf16)
#define TILES ((K_ + KB - 1)/KB)  // 2344 (last tile: 96 valid k, 96%8==0)
#define P1B 128            // pass1 blocks per batch -> 1024 blocks

typedef __attribute__((ext_vector_type(8))) short short8;
typedef __attribute__((ext_vector_type(4))) float f32x4;

// round-to-nearest-even f32 -> bf16 (bit trick, verified rounds 2/5/6/7/9/10/12)
__device__ __forceinline__ unsigned int f2bf(float x) {
    union { float f; unsigned int u; } v; v.f = x;
    unsigned int r = v.u + 0x7FFFu + ((v.u >> 16) & 1u);
    return r >> 16;
}

// prep: zero G/b accumulators; expand wk[b][k]=rsqrt(mas[b][k/3]), smom[b][k]=mom*wk
// (verbatim from round 7, which passed with absmax 0.0625)
__global__ __launch_bounds__(256) void prep_kernel(
    const float* __restrict__ mas, const float* __restrict__ mom,
    float* __restrict__ wk, float* __restrict__ smom,
    float* __restrict__ zbuf, int nzero)
{
    const int i = blockIdx.x*256 + threadIdx.x;
    if (i < nzero) zbuf[i] = 0.0f;
    if (i < B_*K4_) {
        const int b  = i / K4_;
        const int k4 = i - b*K4_;
        const int k  = 4*k4;
        const float* mb = mas + (size_t)b*N_;
        float4 w;
        w.x = rsqrtf(mb[(k+0)/3]);
        w.y = rsqrtf(mb[(k+1)/3]);
        w.z = rsqrtf(mb[(k+2)/3]);
        w.w = rsqrtf(mb[(k+3)/3]);
        const float4 p = ((const float4*)(mom + (size_t)b*K_))[k4];
        float4 s; s.x = p.x*w.x; s.y = p.y*w.y; s.z = p.z*w.z; s.w = p.w*w.w;
        ((float4*)(wk   + (size_t)b*K_))[k4] = w;
        ((float4*)(smom + (size_t)b*K_))[k4] = s;
    }
}

// Pass 1 (MFMA): G = S S^T with S[c,k] = jac[c,k]*wk[k] (bf16 in, fp32 acc);
// b[c] = sum_k S[c,k]*smom[k] in fp32.
// Round-7's pass1 body (phase-1 hoisted to prep; wk/smom read from global with
// L1/L2 broadcast) with round-2's INTERLEAVED tile walk restored — all resident
// blocks stream the same wk/smom window in lockstep -> cache-served.
// LDS hazard structure: write-all -> bar -> read-all -> bar (verified template).
__global__ __launch_bounds__(256) void pass1_mfma(
    const float* __restrict__ jac, const float* __restrict__ wk,
    const float* __restrict__ smom, float* __restrict__ Gws, float* __restrict__ bws)
{
    __shared__ __align__(16) unsigned short sbf[64*KB];  // 16 KB swizzled bf16 tile

    const int b    = blockIdx.x / P1B;
    const int blk  = blockIdx.x % P1B;
    const int tid  = threadIdx.x;
    const int lane = tid & 63;
    const int wv   = tid >> 6;     // wave id 0..3 -> G row-stripe 16*wv
    const int g    = tid & 15;     // staging granule (8 bf16 = 16B)
    const int r0   = tid >> 4;     // staging row base 0..15
    const int lrow = lane & 15;
    const int lkg  = lane >> 4;    // k-group 0..3 within chunk

    const float* jacb = jac  + (size_t)b * C_ * K_;
    const float* wkb  = wk   + (size_t)b * K_;
    const float* smb  = smom + (size_t)b * K_;

    f32x4 acc[4] = {{0.f,0.f,0.f,0.f},{0.f,0.f,0.f,0.f},{0.f,0.f,0.f,0.f},{0.f,0.f,0.f,0.f}};
    float bacc[4] = {0.f, 0.f, 0.f, 0.f};

    for (int tile = blk; tile < TILES; tile += P1B) {
        const int k0 = tile * KB;
        const int kb = k0 + g*8;
        __syncthreads();   // protect sbf reuse (prev phase-3 reads done)

        // phase 2: stage 64 rows x 128 k as bf16, swizzled granules; fp32 b-partials
        if (kb < K_) {
            const float4 w0 = *(const float4*)&wkb[kb];
            const float4 w1 = *(const float4*)&wkb[kb + 4];
            const float4 m0 = *(const float4*)&smb[kb];
            const float4 m1 = *(const float4*)&smb[kb + 4];
            #pragma unroll
            for (int i = 0; i < 4; ++i) {
                const int r = r0 + 16*i;
                const float4 a0 = *(const float4*)&jacb[(size_t)r*K_ + kb];
                const float4 a1 = *(const float4*)&jacb[(size_t)r*K_ + kb + 4];
                const float s0 = a0.x*w0.x, s1 = a0.y*w0.y, s2 = a0.z*w0.z, s3 = a0.w*w0.w;
                const float s4 = a1.x*w1.x, s5 = a1.y*w1.y, s6 = a1.z*w1.z, s7 = a1.w*w1.w;
                bacc[i] += s0*m0.x + s1*m0.y + s2*m0.z + s3*m0.w
                         + s4*m1.x + s5*m1.y + s6*m1.z + s7*m1.w;
                uint4 pk;
                pk.x = (f2bf(s1) << 16) | f2bf(s0);
                pk.y = (f2bf(s3) << 16) | f2bf(s2);
                pk.z = (f2bf(s5) << 16) | f2bf(s4);
                pk.w = (f2bf(s7) << 16) | f2bf(s6);
                *(uint4*)&sbf[r*KB + ((g ^ (r & 15)) * 8)] = pk;
            }
        } else {
            const uint4 pk = make_uint4(0u,0u,0u,0u);
            #pragma unroll
            for (int i = 0; i < 4; ++i) {
                const int r = r0 + 16*i;
                *(uint4*)&sbf[r*KB + ((g ^ (r & 15)) * 8)] = pk;
            }
        }
        __syncthreads();

        // phase 3: MFMA — wave wv computes G[16wv..16wv+15][0..63]
        const int ra = wv*16 + lrow;
        #pragma unroll
        for (int q = 0; q < 4; ++q) {
            const int ga = (q*4 + lkg) ^ (ra & 15);
            const short8 af = *(const short8*)&sbf[ra*KB + ga*8];
            #pragma unroll
            for (int p = 0; p < 4; ++p) {
                const int rb = p*16 + lrow;
                const int gb = (q*4 + lkg) ^ (rb & 15);
                const short8 bf = *(const short8*)&sbf[rb*KB + gb*8];
                acc[p] = __builtin_amdgcn_mfma_f32_16x16x32_bf16(af, bf, acc[p], 0, 0, 0);
            }
        }
    }

    // G partials: C/D layout col=lane&15, row=(lane>>4)*4+reg (m89-verified)
    float* Gb = Gws + b*4096;
    #pragma unroll
    for (int p = 0; p < 4; ++p) {
        #pragma unroll
        for (int reg = 0; reg < 4; ++reg) {
            const int row = 16*wv + lkg*4 + reg;
            const int col = 16*p + lrow;
            atomicAdd(&Gb[row*64 + col], acc[p][reg]);
        }
    }
    // b partials: 16 consecutive lanes share row r0+16i -> butterfly then 1 atomic
    #pragma unroll
    for (int i = 0; i < 4; ++i) {
        float v = bacc[i];
        v += __shfl_xor(v, 1);
        v += __shfl_xor(v, 2);
        v += __shfl_xor(v, 4);
        v += __shfl_xor(v, 8);
        if ((tid & 15) == 0) atomicAdd(&bws[b*64 + r0 + 16*i], v);
    }
}

// Solve (dtm*G) lmd = b per batch; Gaussian elimination (diag-dominant, no pivot)
__global__ __launch_bounds__(256) void solve_kernel(
    const float* __restrict__ Gws, const float* __restrict__ bws,
    const float* __restrict__ dtm, const float* __restrict__ bme,
    float* __restrict__ lmd_ws, float* __restrict__ out_lmd)
{
    __shared__ float A[64*65];   // 64 rows x (64 cols + rhs); stride 65 -> conflict-free
    __shared__ float lmd_s[64];
    const int b = blockIdx.x;
    const int tid = threadIdx.x;
    const float dt = dtm[b];
    const float* Gb = Gws + b*4096;

    for (int e = tid; e < 64*65; e += 256) {
        int j = e / 65, k = e % 65;
        A[e] = (k < 64) ? dt * Gb[j*64 + k] : bws[b*64 + j];
    }
    __syncthreads();

    const int row = tid & 63;
    const int cg  = tid >> 6;     // 4 column groups share a row
    for (int i = 0; i < 64; i++) {
        float f = 0.0f;
        if (row > i) f = A[row*65 + i] / A[i*65 + i];
        int k0 = i + 1;
        k0 += (cg - k0) & 3;      // this group's first column
        if (row > i) {
            for (int k = k0; k <= 64; k += 4)
                A[row*65 + k] -= f * A[i*65 + k];
        }
        __syncthreads();
    }

    for (int i = 63; i >= 0; i--) {
        if (tid == i) lmd_s[i] = A[i*65 + 64] / A[i*65 + i];
        __syncthreads();
        if (tid < i) A[tid*65 + 64] -= A[tid*65 + i] * lmd_s[i];
        __syncthreads();
    }

    if (tid < 64) {
        float l = lmd_s[tid];
        lmd_ws[b*64 + tid] = l;
        out_lmd[b*64 + tid] = bme[b*64 + tid] + l;
    }
}

// Pass 2: mom_out = mom - dtm * lmd^T J   (streaming, float4; verified rounds 1-12)
__global__ __launch_bounds__(256) void apply_kernel(
    const float* __restrict__ jac, const float* __restrict__ mom,
    const float* __restrict__ dtm, const float* __restrict__ lmd_ws,
    float* __restrict__ out)
{
    __shared__ float ls[64];
    const int b   = blockIdx.x / AP_BLK;
    const int blk = blockIdx.x % AP_BLK;
    if (threadIdx.x < 64) ls[threadIdx.x] = lmd_ws[b*64 + threadIdx.x] * dtm[b];
    __syncthreads();
    const int k4 = blk*256 + threadIdx.x;
    if (k4 >= K4_) return;

    const float4* jb = (const float4*)(jac + (size_t)b * C_ * K_);
    float4 a = make_float4(0.f, 0.f, 0.f, 0.f);
    #pragma unroll 8
    for (int c = 0; c < 64; c++) {
        float4 v = jb[(size_t)c * K4_ + k4];
        float l = ls[c];
        a.x -= l*v.x; a.y -= l*v.y; a.z -= l*v.z; a.w -= l*v.w;
    }
    const float4 m = ((const float4*)(mom + (size_t)b * K_))[k4];
    float4 o;
    o.x = m.x + a.x; o.y = m.y + a.y; o.z = m.z + a.z; o.w = m.w + a.w;
    ((float4*)out)[(size_t)b * K4_ + k4] = o;
}

extern "C" void kernel_launch(void* const* d_in, const int* in_sizes, int n_in,
                              void* d_out, int out_size, void* d_ws, size_t ws_size,
                              hipStream_t stream) {
    const float* mom = (const float*)d_in[0];   // [B,N,3]
    const float* mas = (const float*)d_in[1];   // [B,N]
    const float* dtm = (const float*)d_in[2];   // [B]
    const float* jac = (const float*)d_in[3];   // [B,C,N,3]
    const float* bme = (const float*)d_in[4];   // [B,C]
    float* out = (float*)d_out;                 // [B,N,3] then [B,C]

    float* Gws    = (float*)d_ws;               // B*4096
    float* bws    = Gws + B_*4096;              // B*64
    float* lmd_ws = bws + B_*64;                // B*64
    float* wk     = lmd_ws + B_*64;             // B*K_ (16B-aligned)
    float* smom   = wk + (size_t)B_*K_;         // B*K_

    const int nzero = B_*4096 + B_*64;
    prep_kernel<<<(B_*K4_ + 255)/256, 256, 0, stream>>>(mas, mom, wk, smom, Gws, nzero);
    pass1_mfma<<<B_*P1B, 256, 0, stream>>>(jac, wk, smom, Gws, bws);
    solve_kernel<<<B_, 256, 0, stream>>>(Gws, bws, dtm, bme, lmd_ws, out + (size_t)B_*K_);
    apply_kernel<<<B_*AP_BLK, 256, 0, stream>>>(jac, mom, dtm, lmd_ws, out);
}

// Round 14
// 329.785 us; speedup vs baseline: 1.0004x; 1.0004x over previous
//
#include <hip/hip_runtime.h>

#define B_ 8
#define N_ 100000
#define C_ 64
#define K_ 300000          // N*3 flattened reduction dim
#define K4_ (K_/4)         // 75000 float4 per (b,c) row
#define AP_BLK ((K4_ + 255)/256)  // 293

#define KB 128             // pass1 K-tile
#define TILES ((K_ + KB - 1)/KB)  // 2344 (last tile: 96 valid k)
#define P1B 128            // pass1 blocks per batch -> 1024 blocks = 4/CU

typedef __attribute__((ext_vector_type(8))) short short8;
typedef __attribute__((ext_vector_type(4))) float f32x4;

// round-to-nearest-even f32 -> bf16 (bit trick, verified rounds 2/5/6/7/9/10/12/13)
__device__ __forceinline__ unsigned int f2bf(float x) {
    union { float f; unsigned int u; } v; v.f = x;
    unsigned int r = v.u + 0x7FFFu + ((v.u >> 16) & 1u);
    return r >> 16;
}

__global__ __launch_bounds__(256) void zero_kernel(float* __restrict__ p, int n) {
    int i = blockIdx.x*256 + threadIdx.x;
    if (i < n) p[i] = 0.0f;
}

// Pass 1 (MFMA + global_load_lds): G = S S^T, b = S*(w*mom), S = jac*rsqrt(mas).
// Staging: raw fp32 jac -> LDS via global_load_lds_dwordx4 (no VGPR round-trip);
// XOR swizzle applied to the GLOBAL source granule (m173 pattern) so phase-3
// swizzled reads are conflict-free. Scale+convert moved to phase 3 (overlaps MFMA).
// Hazard structure: single buffer, [writes] -> BAR -> [reads] -> BAR (textbook).
// Arithmetic bit-identical to the verified r2 staging (s=a*w, same f2bf).
__global__ __launch_bounds__(256) void pass1_mfma(
    const float* __restrict__ jac, const float* __restrict__ mom,
    const float* __restrict__ mas, float* __restrict__ Gws, float* __restrict__ bws)
{
    __shared__ __align__(16) float sjac[64*KB];  // 32 KB raw fp32, source-swizzled
    __shared__ __align__(16) float w_s[KB];      // rsqrt(mass) per k
    __shared__ __align__(16) float sm_s[KB];     // mom*rsqrt(mass) per k

    const int b    = blockIdx.x / P1B;
    const int blk  = blockIdx.x % P1B;
    const int tid  = threadIdx.x;
    const int lane = tid & 63;
    const int wv   = tid >> 6;     // wave id 0..3 -> G row-stripe 16*wv, stages rows 16wv..16wv+15
    const int lrow = lane & 15;
    const int lkg  = lane >> 4;    // k-group 0..3 within 32-chunk
    const int half = lane >> 5;    // gll: row parity within 1024B inst
    const int s31  = lane & 31;    // gll: LDS slot granule (16B units)

    const float* jacb = jac + (size_t)b * C_ * K_;
    const float* momb = mom + (size_t)b * K_;
    const float* masb = mas + (size_t)b * N_;

    f32x4 acc[4] = {{0.f,0.f,0.f,0.f},{0.f,0.f,0.f,0.f},{0.f,0.f,0.f,0.f},{0.f,0.f,0.f,0.f}};
    float bacc = 0.f;

    for (int tile = blk; tile < TILES; tile += P1B) {
        const int k0 = tile * KB;

        // ---- write segment: phase-1 (w_s/sm_s) + gll staging of raw jac ----
        if (tid < KB) {
            int k = k0 + tid;
            float w = 0.f, sm = 0.f;
            if (k < K_) { w = rsqrtf(masb[k/3]); sm = momb[k] * w; }
            w_s[tid] = w; sm_s[tid] = sm;
        }
        // 8 x global_load_lds_dwordx4 per wave: inst j deposits rows 16wv+2j, +2j+1
        // (1024 B contiguous). Source granule pre-swizzled: gsrc = s31 ^ (row&15).
        // OOB (last tile): clamp address in-buffer; garbage later zeroed by w_s=0.
        #pragma unroll
        for (int j = 0; j < 8; ++j) {
            const int row  = wv*16 + j*2 + half;
            const int gsrc = s31 ^ (row & 15);
            int kk = k0 + gsrc*4;
            kk = (kk > K_ - 4) ? (K_ - 4) : kk;
            const float* gp = &jacb[(size_t)row*K_ + kk];
            float* lp = &sjac[(wv*16 + j*2)*KB];      // wave-uniform base
            __builtin_amdgcn_global_load_lds(
                (const __attribute__((address_space(1))) void*)gp,
                (__attribute__((address_space(3))) void*)lp, 16, 0, 0);
        }
        __syncthreads();   // all LDS writes (ds + gll) complete

        // ---- read segment: scale+convert fragments in-register, MFMA ----
        const int ra = wv*16 + lrow;
        #pragma unroll
        for (int q = 0; q < 4; ++q) {
            const int G0 = q*8 + lkg*2;          // logical 16B granule (even)
            const int s0 = G0 ^ lrow;            // swizzled slot, low half
            const int s1 = (G0 + 1) ^ lrow;      // swizzled slot, high half
            const float4 w0 = *(const float4*)&w_s[G0*4];
            const float4 w1 = *(const float4*)&w_s[G0*4 + 4];
            const float4 m0 = *(const float4*)&sm_s[G0*4];
            const float4 m1 = *(const float4*)&sm_s[G0*4 + 4];
            // A fragment: row ra
            const float4 a0 = *(const float4*)&sjac[ra*KB + s0*4];
            const float4 a1 = *(const float4*)&sjac[ra*KB + s1*4];
            const float s0f = a0.x*w0.x, s1f = a0.y*w0.y, s2f = a0.z*w0.z, s3f = a0.w*w0.w;
            const float s4f = a1.x*w1.x, s5f = a1.y*w1.y, s6f = a1.z*w1.z, s7f = a1.w*w1.w;
            bacc += s0f*m0.x + s1f*m0.y + s2f*m0.z + s3f*m0.w
                  + s4f*m1.x + s5f*m1.y + s6f*m1.z + s7f*m1.w;
            short8 af;
            ((unsigned int*)&af)[0] = (f2bf(s1f) << 16) | f2bf(s0f);
            ((unsigned int*)&af)[1] = (f2bf(s3f) << 16) | f2bf(s2f);
            ((unsigned int*)&af)[2] = (f2bf(s5f) << 16) | f2bf(s4f);
            ((unsigned int*)&af)[3] = (f2bf(s7f) << 16) | f2bf(s6f);
            #pragma unroll
            for (int p = 0; p < 4; ++p) {
                const int rb = p*16 + lrow;       // rb&15 == lrow -> same slots
                const float4 b0 = *(const float4*)&sjac[rb*KB + s0*4];
                const float4 b1 = *(const float4*)&sjac[rb*KB + s1*4];
                const float t0 = b0.x*w0.x, t1 = b0.y*w0.y, t2 = b0.z*w0.z, t3 = b0.w*w0.w;
                const float t4 = b1.x*w1.x, t5 = b1.y*w1.y, t6 = b1.z*w1.z, t7 = b1.w*w1.w;
                short8 bf;
                ((unsigned int*)&bf)[0] = (f2bf(t1) << 16) | f2bf(t0);
                ((unsigned int*)&bf)[1] = (f2bf(t3) << 16) | f2bf(t2);
                ((unsigned int*)&bf)[2] = (f2bf(t5) << 16) | f2bf(t4);
                ((unsigned int*)&bf)[3] = (f2bf(t7) << 16) | f2bf(t6);
                acc[p] = __builtin_amdgcn_mfma_f32_16x16x32_bf16(af, bf, acc[p], 0, 0, 0);
            }
        }
        __syncthreads();   // reads done before next tile's writes
    }

    // G partials: C/D layout col=lane&15, row=(lane>>4)*4+reg (m89-verified)
    float* Gb = Gws + b*4096;
    #pragma unroll
    for (int p = 0; p < 4; ++p) {
        #pragma unroll
        for (int reg = 0; reg < 4; ++reg) {
            const int row = 16*wv + lkg*4 + reg;
            const int col = 16*p + lrow;
            atomicAdd(&Gb[row*64 + col], acc[p][reg]);
        }
    }
    // b partial: lane holds row ra over its (q,lkg) slices; reduce over lkg (r8-verified)
    bacc += __shfl_xor(bacc, 16);
    bacc += __shfl_xor(bacc, 32);
    if (lkg == 0) atomicAdd(&bws[b*64 + wv*16 + lrow], bacc);
}

// Solve (dtm*G) lmd = b per batch; Gaussian elimination (diag-dominant, no pivot)
__global__ __launch_bounds__(256) void solve_kernel(
    const float* __restrict__ Gws, const float* __restrict__ bws,
    const float* __restrict__ dtm, const float* __restrict__ bme,
    float* __restrict__ lmd_ws, float* __restrict__ out_lmd)
{
    __shared__ float A[64*65];   // 64 rows x (64 cols + rhs); stride 65 -> conflict-free
    __shared__ float lmd_s[64];
    const int b = blockIdx.x;
    const int tid = threadIdx.x;
    const float dt = dtm[b];
    const float* Gb = Gws + b*4096;

    for (int e = tid; e < 64*65; e += 256) {
        int j = e / 65, k = e % 65;
        A[e] = (k < 64) ? dt * Gb[j*64 + k] : bws[b*64 + j];
    }
    __syncthreads();

    const int row = tid & 63;
    const int cg  = tid >> 6;     // 4 column groups share a row
    for (int i = 0; i < 64; i++) {
        float f = 0.0f;
        if (row > i) f = A[row*65 + i] / A[i*65 + i];
        int k0 = i + 1;
        k0 += (cg - k0) & 3;      // this group's first column
        if (row > i) {
            for (int k = k0; k <= 64; k += 4)
                A[row*65 + k] -= f * A[i*65 + k];
        }
        __syncthreads();
    }

    for (int i = 63; i >= 0; i--) {
        if (tid == i) lmd_s[i] = A[i*65 + 64] / A[i*65 + i];
        __syncthreads();
        if (tid < i) A[tid*65 + 64] -= A[tid*65 + i] * lmd_s[i];
        __syncthreads();
    }

    if (tid < 64) {
        float l = lmd_s[tid];
        lmd_ws[b*64 + tid] = l;
        out_lmd[b*64 + tid] = bme[b*64 + tid] + l;
    }
}

// Pass 2: mom_out = mom - dtm * lmd^T J   (streaming, float4; verified rounds 1-13)
__global__ __launch_bounds__(256) void apply_kernel(
    const float* __restrict__ jac, const float* __restrict__ mom,
    const float* __restrict__ dtm, const float* __restrict__ lmd_ws,
    float* __restrict__ out)
{
    __shared__ float ls[64];
    const int b   = blockIdx.x / AP_BLK;
    const int blk = blockIdx.x % AP_BLK;
    if (threadIdx.x < 64) ls[threadIdx.x] = lmd_ws[b*64 + threadIdx.x] * dtm[b];
    __syncthreads();
    const int k4 = blk*256 + threadIdx.x;
    if (k4 >= K4_) return;

    const float4* jb = (const float4*)(jac + (size_t)b * C_ * K_);
    float4 a = make_float4(0.f, 0.f, 0.f, 0.f);
    #pragma unroll 8
    for (int c = 0; c < 64; c++) {
        float4 v = jb[(size_t)c * K4_ + k4];
        float l = ls[c];
        a.x -= l*v.x; a.y -= l*v.y; a.z -= l*v.z; a.w -= l*v.w;
    }
    const float4 m = ((const float4*)(mom + (size_t)b * K_))[k4];
    float4 o;
    o.x = m.x + a.x; o.y = m.y + a.y; o.z = m.z + a.z; o.w = m.w + a.w;
    ((float4*)out)[(size_t)b * K4_ + k4] = o;
}

extern "C" void kernel_launch(void* const* d_in, const int* in_sizes, int n_in,
                              void* d_out, int out_size, void* d_ws, size_t ws_size,
                              hipStream_t stream) {
    const float* mom = (const float*)d_in[0];   // [B,N,3]
    const float* mas = (const float*)d_in[1];   // [B,N]
    const float* dtm = (const float*)d_in[2];   // [B]
    const float* jac = (const float*)d_in[3];   // [B,C,N,3]
    const float* bme = (const float*)d_in[4];   // [B,C]
    float* out = (float*)d_out;                 // [B,N,3] then [B,C]

    float* Gws    = (float*)d_ws;               // B*4096
    float* bws    = Gws + B_*4096;              // B*64
    float* lmd_ws = bws + B_*64;                // B*64

    const int nzero = B_*4096 + B_*64;
    zero_kernel<<<(nzero + 255)/256, 256, 0, stream>>>(Gws, nzero);
    pass1_mfma<<<B_*P1B, 256, 0, stream>>>(jac, mom, mas, Gws, bws);
    solve_kernel<<<B_, 256, 0, stream>>>(Gws, bws, dtm, bme, lmd_ws, out + (size_t)B_*K_);
    apply_kernel<<<B_*AP_BLK, 256, 0, stream>>>(jac, mom, dtm, lmd_ws, out);
}

// Round 15
// 307.044 us; speedup vs baseline: 1.0745x; 1.0741x over previous
//
#include <hip/hip_runtime.h>

#define B_ 8
#define N_ 100000
#define C_ 64
#define K_ 300000          // N*3 flattened reduction dim
#define K4_ (K_/4)         // 75000 float4 per (b,c) row
#define AP_BLK ((K4_ + 255)/256)  // 293

#define KB 128             // pass1 K-tile (bf16)
#define TILES ((K_ + KB - 1)/KB)  // 2344 (last tile: 96 valid k, granule-aligned)
#define P1B 128            // pass1 blocks per batch -> 1024 blocks

typedef __attribute__((ext_vector_type(8))) short short8;
typedef __attribute__((ext_vector_type(4))) float f32x4;
typedef __attribute__((ext_vector_type(2))) float f32x2;

// round-to-nearest-even f32 -> bf16 (bit trick, verified rounds 2/5/6/7/9/10/12/13/14)
__device__ __forceinline__ unsigned int f2bf(float x) {
    union { float f; unsigned int u; } v; v.f = x;
    unsigned int r = v.u + 0x7FFFu + ((v.u >> 16) & 1u);
    return r >> 16;
}

__global__ __launch_bounds__(256) void zero_kernel(float* __restrict__ p, int n) {
    int i = blockIdx.x*256 + threadIdx.x;
    if (i < n) p[i] = 0.0f;
}

// Pass 1 (MFMA, 2-barrier): G = S S^T, b = S*(w*mom), S[c,k]=jac[c,k]*rsqrt(mas[k/3]).
// vs r2: phase 1 eliminated — each staging thread computes its granule's w/sm
// inline (mas atoms L1-broadcast across the 16 threads sharing a granule).
// ONE global-load drain per tile, 2 barriers: [write sbf] -> BAR -> [read sbf] -> BAR
// (skeleton refcheck'd in r14). Staging arithmetic bit-identical to r2.
// fp8 J8 pipeline from r9/r10 (convert phase 2, store phase 3): apply reads 4x less.
__global__ __launch_bounds__(256) void pass1_mfma(
    const float* __restrict__ jac, const float* __restrict__ mom,
    const float* __restrict__ mas, float* __restrict__ Gws, float* __restrict__ bws,
    unsigned char* __restrict__ J8)
{
    __shared__ __align__(16) unsigned short sbf[64*KB];  // 16 KB swizzled bf16 tile

    const int b    = blockIdx.x / P1B;
    const int blk  = blockIdx.x % P1B;
    const int tid  = threadIdx.x;
    const int lane = tid & 63;
    const int wv   = tid >> 6;     // wave id 0..3 -> G row-stripe 16*wv
    const int g    = tid & 15;     // staging granule (8 bf16 = 16B)
    const int r0   = tid >> 4;     // staging row base 0..15
    const int lrow = lane & 15;
    const int lkg  = lane >> 4;    // k-group 0..3 within chunk

    const float* jacb = jac + (size_t)b * C_ * K_;
    const float* momb = mom + (size_t)b * K_;
    const float* masb = mas + (size_t)b * N_;
    unsigned char* J8b = J8 + (size_t)b * C_ * K_;

    f32x4 acc[4] = {{0.f,0.f,0.f,0.f},{0.f,0.f,0.f,0.f},{0.f,0.f,0.f,0.f},{0.f,0.f,0.f,0.f}};
    float bacc[4] = {0.f, 0.f, 0.f, 0.f};
    uint2 j8r[4];                  // fp8 payloads, carried phase2 -> phase3

    for (int tile = blk; tile < TILES; tile += P1B) {
        const int k0 = tile * KB;
        const int kb = k0 + g*8;   // this thread's granule base (granule fully in/out)

        // ---- phase 2: inline w/sm + stage 64x128 bf16 (swizzled) + fp8 regs ----
        if (kb < K_) {
            // mas atoms covering k in [kb, kb+8): indices kb/3 .. kb/3+3 (clamped)
            const int i0 = kb / 3;
            const int rr = kb - 3*i0;
            const float R0 = rsqrtf(masb[i0]);
            const float R1 = rsqrtf(masb[i0 + 1]);
            const float R2 = rsqrtf(masb[i0 + 2]);
            const int i3 = (i0 + 3 < N_) ? (i0 + 3) : (N_ - 1);
            const float R3 = rsqrtf(masb[i3]);
            float w[8], sm[8];
            const float4 p0 = *(const float4*)&momb[kb];
            const float4 p1 = *(const float4*)&momb[kb + 4];
            const float pv[8] = {p0.x,p0.y,p0.z,p0.w,p1.x,p1.y,p1.z,p1.w};
            #pragma unroll
            for (int j = 0; j < 8; ++j) {
                const int idx = rr + j;
                w[j]  = idx < 3 ? R0 : idx < 6 ? R1 : idx < 9 ? R2 : R3;
                sm[j] = pv[j] * w[j];
            }
            #pragma unroll
            for (int i = 0; i < 4; ++i) {
                const int r = r0 + 16*i;
                const float4 a0 = *(const float4*)&jacb[(size_t)r*K_ + kb];
                const float4 a1 = *(const float4*)&jacb[(size_t)r*K_ + kb + 4];
                const float av[8] = {a0.x,a0.y,a0.z,a0.w,a1.x,a1.y,a1.z,a1.w};
                {   // fp8 mirror of raw jac for apply (store deferred to phase 3)
                    int lo = __builtin_amdgcn_cvt_pk_fp8_f32(a0.x, a0.y, 0, false);
                    lo     = __builtin_amdgcn_cvt_pk_fp8_f32(a0.z, a0.w, lo, true);
                    int hi = __builtin_amdgcn_cvt_pk_fp8_f32(a1.x, a1.y, 0, false);
                    hi     = __builtin_amdgcn_cvt_pk_fp8_f32(a1.z, a1.w, hi, true);
                    j8r[i].x = (unsigned int)lo; j8r[i].y = (unsigned int)hi;
                }
                float s[8];
                #pragma unroll
                for (int j = 0; j < 8; ++j) {
                    s[j] = av[j] * w[j];
                    bacc[i] += s[j] * sm[j];
                }
                uint4 pk;
                pk.x = (f2bf(s[1]) << 16) | f2bf(s[0]);
                pk.y = (f2bf(s[3]) << 16) | f2bf(s[2]);
                pk.z = (f2bf(s[5]) << 16) | f2bf(s[4]);
                pk.w = (f2bf(s[7]) << 16) | f2bf(s[6]);
                *(uint4*)&sbf[r*KB + ((g ^ (r & 15)) * 8)] = pk;
            }
        } else {
            const uint4 pk = make_uint4(0u,0u,0u,0u);
            #pragma unroll
            for (int i = 0; i < 4; ++i) {
                const int r = r0 + 16*i;
                *(uint4*)&sbf[r*KB + ((g ^ (r & 15)) * 8)] = pk;
            }
        }
        __syncthreads();   // all sbf writes complete

        // ---- phase 3: J8 stores (retire under MFMA, r10-verified placement) + MFMA ----
        if (kb < K_) {
            #pragma unroll
            for (int i = 0; i < 4; ++i)
                *(uint2*)&J8b[(size_t)(r0 + 16*i)*K_ + kb] = j8r[i];
        }

        const int ra = wv*16 + lrow;
        #pragma unroll
        for (int q = 0; q < 4; ++q) {
            const int ga = (q*4 + lkg) ^ (ra & 15);
            const short8 af = *(const short8*)&sbf[ra*KB + ga*8];
            #pragma unroll
            for (int p = 0; p < 4; ++p) {
                const int rb = p*16 + lrow;
                const int gb = (q*4 + lkg) ^ (rb & 15);
                const short8 bf = *(const short8*)&sbf[rb*KB + gb*8];
                acc[p] = __builtin_amdgcn_mfma_f32_16x16x32_bf16(af, bf, acc[p], 0, 0, 0);
            }
        }
        __syncthreads();   // sbf reads done before next tile's writes
    }

    // G partials: C/D layout col=lane&15, row=(lane>>4)*4+reg (m89-verified)
    float* Gb = Gws + b*4096;
    #pragma unroll
    for (int p = 0; p < 4; ++p) {
        #pragma unroll
        for (int reg = 0; reg < 4; ++reg) {
            const int row = 16*wv + lkg*4 + reg;
            const int col = 16*p + lrow;
            atomicAdd(&Gb[row*64 + col], acc[p][reg]);
        }
    }
    // b partials: 16 consecutive lanes share row r0+16i -> butterfly then 1 atomic
    #pragma unroll
    for (int i = 0; i < 4; ++i) {
        float v = bacc[i];
        v += __shfl_xor(v, 1);
        v += __shfl_xor(v, 2);
        v += __shfl_xor(v, 4);
        v += __shfl_xor(v, 8);
        if ((tid & 15) == 0) atomicAdd(&bws[b*64 + r0 + 16*i], v);
    }
}

// Solve (dtm*G) lmd = b per batch; Gaussian elimination (diag-dominant, no pivot)
__global__ __launch_bounds__(256) void solve_kernel(
    const float* __restrict__ Gws, const float* __restrict__ bws,
    const float* __restrict__ dtm, const float* __restrict__ bme,
    float* __restrict__ lmd_ws, float* __restrict__ out_lmd)
{
    __shared__ float A[64*65];   // 64 rows x (64 cols + rhs); stride 65 -> conflict-free
    __shared__ float lmd_s[64];
    const int b = blockIdx.x;
    const int tid = threadIdx.x;
    const float dt = dtm[b];
    const float* Gb = Gws + b*4096;

    for (int e = tid; e < 64*65; e += 256) {
        int j = e / 65, k = e % 65;
        A[e] = (k < 64) ? dt * Gb[j*64 + k] : bws[b*64 + j];
    }
    __syncthreads();

    const int row = tid & 63;
    const int cg  = tid >> 6;     // 4 column groups share a row
    for (int i = 0; i < 64; i++) {
        float f = 0.0f;
        if (row > i) f = A[row*65 + i] / A[i*65 + i];
        int k0 = i + 1;
        k0 += (cg - k0) & 3;      // this group's first column
        if (row > i) {
            for (int k = k0; k <= 64; k += 4)
                A[row*65 + k] -= f * A[i*65 + k];
        }
        __syncthreads();
    }

    for (int i = 63; i >= 0; i--) {
        if (tid == i) lmd_s[i] = A[i*65 + 64] / A[i*65 + i];
        __syncthreads();
        if (tid < i) A[tid*65 + 64] -= A[tid*65 + i] * lmd_s[i];
        __syncthreads();
    }

    if (tid < 64) {
        float l = lmd_s[tid];
        lmd_ws[b*64 + tid] = l;
        out_lmd[b*64 + tid] = bme[b*64 + tid] + l;
    }
}

// Pass 2 (fp8): mom_out = mom - dtm * lmd^T J, J read as e4m3 (r9-verified)
__global__ __launch_bounds__(256) void apply8_kernel(
    const unsigned char* __restrict__ J8, const float* __restrict__ mom,
    const float* __restrict__ dtm, const float* __restrict__ lmd_ws,
    float* __restrict__ out)
{
    __shared__ float ls[64];
    const int b   = blockIdx.x / AP_BLK;
    const int blk = blockIdx.x % AP_BLK;
    if (threadIdx.x < 64) ls[threadIdx.x] = lmd_ws[b*64 + threadIdx.x] * dtm[b];
    __syncthreads();
    const int k4 = blk*256 + threadIdx.x;
    if (k4 >= K4_) return;

    const unsigned char* jb = J8 + (size_t)b * C_ * K_;
    float4 a = make_float4(0.f, 0.f, 0.f, 0.f);
    #pragma unroll 8
    for (int c = 0; c < 64; c++) {
        const unsigned int u = *(const unsigned int*)&jb[(size_t)c * K_ + 4*k4];
        const f32x2 f01 = __builtin_amdgcn_cvt_pk_f32_fp8(u, false);
        const f32x2 f23 = __builtin_amdgcn_cvt_pk_f32_fp8(u, true);
        const float l = ls[c];
        a.x -= l*f01[0]; a.y -= l*f01[1]; a.z -= l*f23[0]; a.w -= l*f23[1];
    }
    const float4 m = ((const float4*)(mom + (size_t)b * K_))[k4];
    float4 o;
    o.x = m.x + a.x; o.y = m.y + a.y; o.z = m.z + a.z; o.w = m.w + a.w;
    ((float4*)out)[(size_t)b * K4_ + k4] = o;
}

extern "C" void kernel_launch(void* const* d_in, const int* in_sizes, int n_in,
                              void* d_out, int out_size, void* d_ws, size_t ws_size,
                              hipStream_t stream) {
    const float* mom = (const float*)d_in[0];   // [B,N,3]
    const float* mas = (const float*)d_in[1];   // [B,N]
    const float* dtm = (const float*)d_in[2];   // [B]
    const float* jac = (const float*)d_in[3];   // [B,C,N,3]
    const float* bme = (const float*)d_in[4];   // [B,C]
    float* out = (float*)d_out;                 // [B,N,3] then [B,C]

    float* Gws    = (float*)d_ws;               // B*4096
    float* bws    = Gws + B_*4096;              // B*64
    float* lmd_ws = bws + B_*64;                // B*64
    unsigned char* J8 = (unsigned char*)(lmd_ws + B_*64);  // B*C*K fp8 (153.6 MB)

    const int nzero = B_*4096 + B_*64;
    zero_kernel<<<(nzero + 255)/256, 256, 0, stream>>>(Gws, nzero);
    pass1_mfma<<<B_*P1B, 256, 0, stream>>>(jac, mom, mas, Gws, bws, J8);
    solve_kernel<<<B_, 256, 0, stream>>>(Gws, bws, dtm, bme, lmd_ws, out + (size_t)B_*K_);
    apply8_kernel<<<B_*AP_BLK, 256, 0, stream>>>(J8, mom, dtm, lmd_ws, out);
}

// Round 16
// 299.653 us; speedup vs baseline: 1.1010x; 1.0247x over previous
//
#include <hip/hip_runtime.h>

#define B_ 8
#define N_ 100000
#define C_ 64
#define K_ 300000          // N*3 flattened reduction dim
#define K4_ (K_/4)         // 75000 float4 per (b,c) row
#define AP_BLK ((K4_ + 255)/256)  // 293

#define KB 128             // pass1 K-tile (bf16)
#define TILES ((K_ + KB - 1)/KB)  // 2344 (last tile: 96 valid k)
#define P1B 128            // pass1 blocks per batch -> 1024 blocks

typedef __attribute__((ext_vector_type(8))) short short8;
typedef __attribute__((ext_vector_type(4))) float f32x4;
typedef __attribute__((ext_vector_type(2))) float f32x2;

// round-to-nearest-even f32 -> bf16 (bit trick, verified rounds 2/5/6/7/9/10/12-15)
__device__ __forceinline__ unsigned int f2bf(float x) {
    union { float f; unsigned int u; } v; v.f = x;
    unsigned int r = v.u + 0x7FFFu + ((v.u >> 16) & 1u);
    return r >> 16;
}

__global__ __launch_bounds__(256) void zero_kernel(float* __restrict__ p, int n) {
    int i = blockIdx.x*256 + threadIdx.x;
    if (i < n) p[i] = 0.0f;
}

// Pass 1 (MFMA): G = S S^T, b = S*(w*mom), S[c,k] = jac[c,k]*rsqrt(mas[k/3]).
// Round-2 verified template (3 barriers/tile, single LDS tile buffer) + fp8 J8
// mirror of raw jac for the apply pass (r9 placement — best measured config).
__global__ __launch_bounds__(256) void pass1_mfma(
    const float* __restrict__ jac, const float* __restrict__ mom,
    const float* __restrict__ mas, float* __restrict__ Gws, float* __restrict__ bws,
    unsigned char* __restrict__ J8)
{
    __shared__ __align__(16) unsigned short sbf[64*KB];  // 16 KB swizzled bf16 tile
    __shared__ __align__(16) float w_s[KB];              // rsqrt(mass) per k
    __shared__ __align__(16) float sm_s[KB];             // mom*rsqrt(mass) per k

    const int b    = blockIdx.x / P1B;
    const int blk  = blockIdx.x % P1B;
    const int tid  = threadIdx.x;
    const int lane = tid & 63;
    const int wv   = tid >> 6;     // wave id 0..3 -> G row-stripe 16*wv
    const int g    = tid & 15;     // staging granule (8 bf16 = 16B)
    const int r0   = tid >> 4;     // staging row base 0..15
    const int lrow = lane & 15;
    const int lkg  = lane >> 4;    // k-group 0..3 within chunk

    const float* jacb = jac + (size_t)b * C_ * K_;
    const float* momb = mom + (size_t)b * K_;
    const float* masb = mas + (size_t)b * N_;
    unsigned char* J8b = J8 + (size_t)b * C_ * K_;

    f32x4 acc[4] = {{0.f,0.f,0.f,0.f},{0.f,0.f,0.f,0.f},{0.f,0.f,0.f,0.f},{0.f,0.f,0.f,0.f}};
    float bacc[4] = {0.f, 0.f, 0.f, 0.f};

    for (int tile = blk; tile < TILES; tile += P1B) {
        const int k0 = tile * KB;

        // phase 1: per-k weights + scaled momentum (128 values)
        if (tid < KB) {
            int k = k0 + tid;
            float w = 0.f, sm = 0.f;
            if (k < K_) { w = rsqrtf(masb[k/3]); sm = momb[k] * w; }
            w_s[tid] = w; sm_s[tid] = sm;
        }
        __syncthreads();

        // phase 2: stage 64 rows x 128 k as bf16, swizzled granules; fp32 b-partials;
        //          emit raw jac as fp8 e4m3 (OCP on gfx950) for the apply pass
        #pragma unroll
        for (int i = 0; i < 4; ++i) {
            const int r  = r0 + 16*i;
            const int kb = k0 + g*8;
            uint4 pk = make_uint4(0u, 0u, 0u, 0u);
            if (kb < K_) {
                const float4 a0 = *(const float4*)&jacb[(size_t)r*K_ + kb];
                const float4 a1 = *(const float4*)&jacb[(size_t)r*K_ + kb + 4];
                const float4 w0 = *(const float4*)&w_s[g*8];
                const float4 w1 = *(const float4*)&w_s[g*8 + 4];
                const float4 m0 = *(const float4*)&sm_s[g*8];
                const float4 m1 = *(const float4*)&sm_s[g*8 + 4];
                // fp8 mirror of raw jac (fire-and-forget, no dependency)
                uint2 j8;
                {
                    int lo = __builtin_amdgcn_cvt_pk_fp8_f32(a0.x, a0.y, 0, false);
                    lo     = __builtin_amdgcn_cvt_pk_fp8_f32(a0.z, a0.w, lo, true);
                    int hi = __builtin_amdgcn_cvt_pk_fp8_f32(a1.x, a1.y, 0, false);
                    hi     = __builtin_amdgcn_cvt_pk_fp8_f32(a1.z, a1.w, hi, true);
                    j8.x = (unsigned int)lo; j8.y = (unsigned int)hi;
                }
                *(uint2*)&J8b[(size_t)r*K_ + kb] = j8;
                const float s0 = a0.x*w0.x, s1 = a0.y*w0.y, s2 = a0.z*w0.z, s3 = a0.w*w0.w;
                const float s4 = a1.x*w1.x, s5 = a1.y*w1.y, s6 = a1.z*w1.z, s7 = a1.w*w1.w;
                bacc[i] += s0*m0.x + s1*m0.y + s2*m0.z + s3*m0.w
                         + s4*m1.x + s5*m1.y + s6*m1.z + s7*m1.w;
                pk.x = (f2bf(s1) << 16) | f2bf(s0);
                pk.y = (f2bf(s3) << 16) | f2bf(s2);
                pk.z = (f2bf(s5) << 16) | f2bf(s4);
                pk.w = (f2bf(s7) << 16) | f2bf(s6);
            }
            *(uint4*)&sbf[r*KB + ((g ^ (r & 15)) * 8)] = pk;
        }
        __syncthreads();

        // phase 3: MFMA — wave wv computes G[16wv..16wv+15][0..63]
        const int ra = wv*16 + lrow;
        #pragma unroll
        for (int q = 0; q < 4; ++q) {
            const int ga = (q*4 + lkg) ^ (ra & 15);
            const short8 af = *(const short8*)&sbf[ra*KB + ga*8];
            #pragma unroll
            for (int p = 0; p < 4; ++p) {
                const int rb = p*16 + lrow;
                const int gb = (q*4 + lkg) ^ (rb & 15);
                const short8 bf = *(const short8*)&sbf[rb*KB + gb*8];
                acc[p] = __builtin_amdgcn_mfma_f32_16x16x32_bf16(af, bf, acc[p], 0, 0, 0);
            }
        }
        // no barrier needed here: next phase-1 writes w_s/sm_s (disjoint from sbf);
        // the barrier after next phase-1 orders sbf reuse.
    }

    // G partials: C/D layout col=lane&15, row=(lane>>4)*4+reg (m89-verified)
    float* Gb = Gws + b*4096;
    #pragma unroll
    for (int p = 0; p < 4; ++p) {
        #pragma unroll
        for (int reg = 0; reg < 4; ++reg) {
            const int row = 16*wv + lkg*4 + reg;
            const int col = 16*p + lrow;
            atomicAdd(&Gb[row*64 + col], acc[p][reg]);
        }
    }
    // b partials: 16 consecutive lanes share row r0+16i -> butterfly then 1 atomic
    #pragma unroll
    for (int i = 0; i < 4; ++i) {
        float v = bacc[i];
        v += __shfl_xor(v, 1);
        v += __shfl_xor(v, 2);
        v += __shfl_xor(v, 4);
        v += __shfl_xor(v, 8);
        if ((tid & 15) == 0) atomicAdd(&bws[b*64 + r0 + 16*i], v);
    }
}

// Solve (dtm*G) lmd = b per batch; Gaussian elimination (diag-dominant, no pivot)
__global__ __launch_bounds__(256) void solve_kernel(
    const float* __restrict__ Gws, const float* __restrict__ bws,
    const float* __restrict__ dtm, const float* __restrict__ bme,
    float* __restrict__ lmd_ws, float* __restrict__ out_lmd)
{
    __shared__ float A[64*65];   // 64 rows x (64 cols + rhs); stride 65 -> conflict-free
    __shared__ float lmd_s[64];
    const int b = blockIdx.x;
    const int tid = threadIdx.x;
    const float dt = dtm[b];
    const float* Gb = Gws + b*4096;

    for (int e = tid; e < 64*65; e += 256) {
        int j = e / 65, k = e % 65;
        A[e] = (k < 64) ? dt * Gb[j*64 + k] : bws[b*64 + j];
    }
    __syncthreads();

    const int row = tid & 63;
    const int cg  = tid >> 6;     // 4 column groups share a row
    for (int i = 0; i < 64; i++) {
        float f = 0.0f;
        if (row > i) f = A[row*65 + i] / A[i*65 + i];
        int k0 = i + 1;
        k0 += (cg - k0) & 3;      // this group's first column
        if (row > i) {
            for (int k = k0; k <= 64; k += 4)
                A[row*65 + k] -= f * A[i*65 + k];
        }
        __syncthreads();
    }

    for (int i = 63; i >= 0; i--) {
        if (tid == i) lmd_s[i] = A[i*65 + 64] / A[i*65 + i];
        __syncthreads();
        if (tid < i) A[tid*65 + 64] -= A[tid*65 + i] * lmd_s[i];
        __syncthreads();
    }

    if (tid < 64) {
        float l = lmd_s[tid];
        lmd_ws[b*64 + tid] = l;
        out_lmd[b*64 + tid] = bme[b*64 + tid] + l;
    }
}

// Pass 2 (fp8): mom_out = mom - dtm * lmd^T J, J read as e4m3 (4x less traffic)
__global__ __launch_bounds__(256) void apply8_kernel(
    const unsigned char* __restrict__ J8, const float* __restrict__ mom,
    const float* __restrict__ dtm, const float* __restrict__ lmd_ws,
    float* __restrict__ out)
{
    __shared__ float ls[64];
    const int b   = blockIdx.x / AP_BLK;
    const int blk = blockIdx.x % AP_BLK;
    if (threadIdx.x < 64) ls[threadIdx.x] = lmd_ws[b*64 + threadIdx.x] * dtm[b];
    __syncthreads();
    const int k4 = blk*256 + threadIdx.x;
    if (k4 >= K4_) return;

    const unsigned char* jb = J8 + (size_t)b * C_ * K_;
    float4 a = make_float4(0.f, 0.f, 0.f, 0.f);
    #pragma unroll 8
    for (int c = 0; c < 64; c++) {
        const unsigned int u = *(const unsigned int*)&jb[(size_t)c * K_ + 4*k4];
        const f32x2 f01 = __builtin_amdgcn_cvt_pk_f32_fp8(u, false);
        const f32x2 f23 = __builtin_amdgcn_cvt_pk_f32_fp8(u, true);
        const float l = ls[c];
        a.x -= l*f01[0]; a.y -= l*f01[1]; a.z -= l*f23[0]; a.w -= l*f23[1];
    }
    const float4 m = ((const float4*)(mom + (size_t)b * K_))[k4];
    float4 o;
    o.x = m.x + a.x; o.y = m.y + a.y; o.z = m.z + a.z; o.w = m.w + a.w;
    ((float4*)out)[(size_t)b * K4_ + k4] = o;
}

extern "C" void kernel_launch(void* const* d_in, const int* in_sizes, int n_in,
                              void* d_out, int out_size, void* d_ws, size_t ws_size,
                              hipStream_t stream) {
    const float* mom = (const float*)d_in[0];   // [B,N,3]
    const float* mas = (const float*)d_in[1];   // [B,N]
    const float* dtm = (const float*)d_in[2];   // [B]
    const float* jac = (const float*)d_in[3];   // [B,C,N,3]
    const float* bme = (const float*)d_in[4];   // [B,C]
    float* out = (float*)d_out;                 // [B,N,3] then [B,C]

    float* Gws    = (float*)d_ws;               // B*4096
    float* bws    = Gws + B_*4096;              // B*64
    float* lmd_ws = bws + B_*64;                // B*64
    unsigned char* J8 = (unsigned char*)(lmd_ws + B_*64);  // B*C*K fp8 (153.6 MB)

    const int nzero = B_*4096 + B_*64;
    zero_kernel<<<(nzero + 255)/256, 256, 0, stream>>>(Gws, nzero);
    pass1_mfma<<<B_*P1B, 256, 0, stream>>>(jac, mom, mas, Gws, bws, J8);
    solve_kernel<<<B_, 256, 0, stream>>>(Gws, bws, dtm, bme, lmd_ws, out + (size_t)B_*K_);
    apply8_kernel<<<B_*AP_BLK, 256, 0, stream>>>(J8, mom, dtm, lmd_ws, out);
}